// Round 11
// baseline (102.799 us; speedup 1.0000x reference)
//
#include <hip/hip_runtime.h>

typedef __attribute__((ext_vector_type(8))) short bf16x8;
typedef __attribute__((ext_vector_type(4))) float f32x4;
typedef __attribute__((ext_vector_type(4))) unsigned short us4;

#define LOG2E 1.44269504088896f
#define GP(p) (const __attribute__((address_space(1))) void*)(p)
#define LP(p) (__attribute__((address_space(3))) void*)(p)

__device__ inline unsigned short f2bf(float f) {
    unsigned u = __float_as_uint(f);
    u += 0x7fffu + ((u >> 16) & 1u);
    return (unsigned short)(u >> 16);
}

__device__ inline unsigned cvt_pk_bf16(float lo, float hi) {
    unsigned r;
    asm("v_cvt_pk_bf16_f32 %0, %1, %2" : "=v"(r) : "v"(lo), "v"(hi));
    return r;
}

// ---------------- fused fp32 -> bf16 convert of x, qkv_w, proj_w ----------------
__global__ void cvt3_kernel(const float* __restrict__ x, const float* __restrict__ qw,
                            const float* __restrict__ pw,
                            unsigned short* __restrict__ xb, unsigned short* __restrict__ wqkv,
                            unsigned short* __restrict__ wproj) {
    const int nthreads = gridDim.x * blockDim.x;
    for (int i = blockIdx.x * blockDim.x + threadIdx.x; i < 2097152; i += nthreads) {
        const float* src; unsigned short* dst; int off;
        if (i < 1048576)      { src = x;  dst = xb;    off = i; }
        else if (i < 1835008) { src = qw; dst = wqkv;  off = i - 1048576; }
        else                  { src = pw; dst = wproj; off = i - 1835008; }
        const float4 v = *reinterpret_cast<const float4*>(src + off * 4);
        us4 o;
        o.x = f2bf(v.x); o.y = f2bf(v.y); o.z = f2bf(v.z); o.w = f2bf(v.w);
        *reinterpret_cast<us4*>(dst + off * 4) = o;
    }
}

// ---------------- GEMM1: 256^2 tile, BK=64, 8-phase counted-vmcnt schedule ----------
// 512 thr = 8 waves (2M x 4N); wave output 128x64 -> acc[8][4]. LDS 128 KiB:
// A[2buf][256][64], B[2buf][256][64] bf16. Per iter: 2 K-tiles, 8 phases of
// {12 ds_read_b128, stage 1 half-set (2 gload_lds), barrier, lgkmcnt(0), 16 MFMA,
// [vmcnt(4) at ph4/ph8], barrier}. Half-sets match quadrant read-sets:
// A-set h = rows {h*64..h*64+64} u {128+h*64..}; B-set h = rows {h*32..h*32+32 mod 64}.
// Swizzle: LDS slot s of row r holds global slot s^(r&7) (inverse-swizzled source,
// linear gload dest, same XOR on read) -> 2-way bank aliasing (free).
__global__ __launch_bounds__(512, 2) void gemm_qkv_kernel(
        const unsigned short* __restrict__ A, const unsigned short* __restrict__ Bw,
        const float* __restrict__ bias, const float* __restrict__ cosT, const float* __restrict__ sinT,
        unsigned short* __restrict__ Qb, unsigned short* __restrict__ Kb, unsigned short* __restrict__ Vt) {
    __shared__ __align__(16) unsigned short AL[2 * 16384];
    __shared__ __align__(16) unsigned short BL[2 * 16384];
    const int tid = threadIdx.x;
    const int lane = tid & 63, wid = tid >> 6;
    const int wm = wid >> 2, wn = wid & 3;
    const int lr = lane & 15, lg = lane >> 4;
    const int tm = blockIdx.y, tn = blockIdx.x;

    const int srow = tid >> 3;                          // 0..63
    const int gslot = ((tid & 7) ^ (srow & 7)) * 8;     // swizzled source slot (shorts)
    const int brow1 = (srow & 31) + ((srow >> 5) << 6); // B-set row mapping, call 1
    const int brow2 = ((srow + 64) & 31) + (((srow + 64) >> 5) << 6);
    const unsigned short* Agb = A + (size_t)tm * 256 * 1024;
    const unsigned short* Bgb = Bw + (size_t)tn * 256 * 1024;

    f32x4 acc[8][4];
#pragma unroll
    for (int i = 0; i < 8; i++)
#pragma unroll
        for (int j = 0; j < 4; j++)
#pragma unroll
            for (int q = 0; q < 4; q++) acc[i][j][q] = 0.f;

// A half-set H: rows {H*64 + 0..63} u {128 + H*64 + 0..63}; LDS linear dests.
#define STGA(BUF, H, K0) do { \
    const unsigned short* _s = Agb + (size_t)((H) * 64 + srow) * 1024 + (K0) + gslot; \
    __builtin_amdgcn_global_load_lds(GP(_s), LP(AL + (BUF) * 16384 + (H) * 4096 + tid * 8), 16, 0, 0); \
    __builtin_amdgcn_global_load_lds(GP(_s + 131072), LP(AL + (BUF) * 16384 + (H) * 4096 + 8192 + tid * 8), 16, 0, 0); \
} while (0)
// B half-set H: rows {r : (r mod 64) in [H*32, H*32+32)}.
#define STGB(BUF, H, K0) do { \
    __builtin_amdgcn_global_load_lds(GP(Bgb + (size_t)(brow1 + (H) * 32) * 1024 + (K0) + gslot), \
        LP(BL + (BUF) * 16384 + (brow1 + (H) * 32) * 64 + (tid & 7) * 8), 16, 0, 0); \
    __builtin_amdgcn_global_load_lds(GP(Bgb + (size_t)(brow2 + (H) * 32) * 1024 + (K0) + gslot), \
        LP(BL + (BUF) * 16384 + (brow2 + (H) * 32) * 64 + (tid & 7) * 8), 16, 0, 0); \
} while (0)

#define PH(BUF, MH, NH, STG_STMT, VM) do { \
    bf16x8 paf[4][2], pbf[2][2]; \
    const unsigned short* _Ab = AL + (BUF) * 16384; \
    const unsigned short* _Bb = BL + (BUF) * 16384; \
    _Pragma("unroll") \
    for (int mr = 0; mr < 4; mr++) \
        _Pragma("unroll") \
        for (int kk = 0; kk < 2; kk++) { \
            const int rw = wm * 128 + (MH) * 64 + mr * 16 + lr; \
            paf[mr][kk] = *reinterpret_cast<const bf16x8*>(_Ab + rw * 64 + ((kk * 4 + lg) ^ (rw & 7)) * 8); \
        } \
    _Pragma("unroll") \
    for (int nf = 0; nf < 2; nf++) \
        _Pragma("unroll") \
        for (int kk = 0; kk < 2; kk++) { \
            const int rw = wn * 64 + (NH) * 32 + nf * 16 + lr; \
            pbf[nf][kk] = *reinterpret_cast<const bf16x8*>(_Bb + rw * 64 + ((kk * 4 + lg) ^ (rw & 7)) * 8); \
        } \
    STG_STMT; \
    __builtin_amdgcn_s_barrier(); \
    asm volatile("s_waitcnt lgkmcnt(0)" ::: "memory"); \
    __builtin_amdgcn_sched_barrier(0); \
    __builtin_amdgcn_s_setprio(1); \
    _Pragma("unroll") \
    for (int mr = 0; mr < 4; mr++) \
        _Pragma("unroll") \
        for (int nf = 0; nf < 2; nf++) \
            _Pragma("unroll") \
            for (int kk = 0; kk < 2; kk++) \
                acc[(MH) * 4 + mr][(NH) * 2 + nf] = __builtin_amdgcn_mfma_f32_16x16x32_bf16( \
                    paf[mr][kk], pbf[nf][kk], acc[(MH) * 4 + mr][(NH) * 2 + nf], 0, 0, 0); \
    __builtin_amdgcn_s_setprio(0); \
    if (VM) asm volatile("s_waitcnt vmcnt(4)" ::: "memory"); \
    __builtin_amdgcn_s_barrier(); \
    __builtin_amdgcn_sched_barrier(0); \
} while (0)

    // prologue: tile0 all 4 half-sets, tile1 A-set0 + B-set1; keep t1's 4 loads in flight
    STGA(0, 0, 0);
    STGB(0, 1, 0);
    STGA(0, 1, 0);
    STGB(0, 0, 0);
    STGA(1, 0, 64);
    STGB(1, 1, 64);
    asm volatile("s_waitcnt vmcnt(4)" ::: "memory");
    __builtin_amdgcn_s_barrier();
    __builtin_amdgcn_sched_barrier(0);

#pragma unroll 1
    for (int i = 0; i < 8; i++) {
        const int t1k = (2 * i + 1) * 64;
        const int t2k = (2 * i + 2 < 16 ? 2 * i + 2 : 15) * 64;   // clamped (tail writes dead)
        const int t3k = (2 * i + 3 < 16 ? 2 * i + 3 : 15) * 64;
        PH(0, 0, 0, STGA(1, 1, t1k), 0);   // ph1: A-set1(t+1)
        PH(0, 0, 1, STGB(1, 0, t1k), 0);   // ph2: B-set0(t+1)
        PH(0, 1, 1, STGA(0, 0, t2k), 0);   // ph3: A-set0(t+2)
        PH(0, 1, 0, STGB(0, 1, t2k), 1);   // ph4: B-set1(t+2) + vmcnt(4)
        PH(1, 0, 0, STGA(0, 1, t2k), 0);   // ph5: A-set1(t+2)
        PH(1, 0, 1, STGB(0, 0, t2k), 0);   // ph6: B-set0(t+2)
        PH(1, 1, 1, STGA(1, 0, t3k), 0);   // ph7: A-set0(t+3)
        PH(1, 1, 0, STGB(1, 1, t3k), 1);   // ph8: B-set1(t+3) + vmcnt(4)
    }
#undef PH
#undef STGA
#undef STGB

    // epilogue: bias + RoPE + scatter. col base = tn*256 + wn*64 (head-aligned).
    const int cbase = tn * 256 + wn * 64;
    const int sec = cbase >> 10;                   // 0=q 1=k 2=v
    const int h = (cbase & 1023) >> 6;
    float bias_c[4];
#pragma unroll
    for (int nf = 0; nf < 4; nf++) bias_c[nf] = bias[cbase + nf * 16 + lr];

    if (sec == 2) {
#pragma unroll
        for (int mr8 = 0; mr8 < 8; mr8++) {
            const int m0 = tm * 256 + wm * 128 + mr8 * 16 + lg * 4;
            const int b = m0 >> 10, n0 = m0 & 1023;
#pragma unroll
            for (int nf = 0; nf < 4; nf++) {
                const int d = nf * 16 + lr;
                us4 pk;
                pk.x = f2bf(acc[mr8][nf][0] + bias_c[nf]); pk.y = f2bf(acc[mr8][nf][1] + bias_c[nf]);
                pk.z = f2bf(acc[mr8][nf][2] + bias_c[nf]); pk.w = f2bf(acc[mr8][nf][3] + bias_c[nf]);
                *reinterpret_cast<us4*>(Vt + ((size_t)((b * 16 + h) * 64 + d)) * 1024 + n0) = pk;
            }
        }
    } else {
#pragma unroll
        for (int mr8 = 0; mr8 < 8; mr8++) {
#pragma unroll
            for (int r = 0; r < 4; r++) {
                const int m = tm * 256 + wm * 128 + mr8 * 16 + lg * 4 + r;
                const int b = m >> 10, n = m & 1023;
                float vals[4];
#pragma unroll
                for (int nf = 0; nf < 4; nf++) vals[nf] = acc[mr8][nf][r] + bias_c[nf];
#pragma unroll
                for (int nf = 0; nf < 4; nf++) {
                    const int d = nf * 16 + lr;
                    const float c = cosT[n * 64 + d];
                    const float s = sinT[n * 64 + d];
                    const float pr = vals[nf ^ 2];         // paired element d ^ 32
                    float outv = vals[nf] * c + (d < 32 ? -pr : pr) * s;
                    if (sec == 0) outv *= 0.125f * LOG2E;  // fold scale + log2(e) into Q
                    unsigned short* dst = (sec == 0) ? Qb : Kb;
                    dst[((size_t)((b * 16 + h) * 1024 + n)) * 64 + d] = f2bf(outv);
                }
            }
        }
    }
}

// ---------------- flash attention: NO-MAX softmax, ones-MFMA l, staggered staging ----
__global__ __launch_bounds__(256, 4) void attn_kernel(
        const unsigned short* __restrict__ Qb, const unsigned short* __restrict__ Kb,
        const unsigned short* __restrict__ Vt, unsigned short* __restrict__ AO) {
    __shared__ __align__(16) unsigned short Kbuf[2][4096];
    __shared__ __align__(16) unsigned short Vbuf[2][4096];
    const int tid = threadIdx.x, lane = tid & 63, wv = tid >> 6;
    const int bh = blockIdx.x, qt = blockIdx.y;
    const int qbase = qt * 64 + wv * 16;
    const unsigned short* Qp = Qb + (size_t)bh * 65536;
    const unsigned short* Kp = Kb + (size_t)bh * 65536;
    const unsigned short* Vp = Vt + (size_t)bh * 65536;
    const int lr = lane & 15, lg = lane >> 4;
    const int koff = (lr >> 2) * 8 + (lr & 3);     // lane part of pi

    const int s1 = tid, s2 = tid + 256;
    const int r1 = s1 >> 3, r2 = s2 >> 3;
    const int sc1 = (s1 & 7) ^ ((r1 & 3) | ((r1 >> 1) & 4));
    const int sc2 = (s2 & 7) ^ ((r2 & 3) | ((r2 >> 1) & 4));
    const unsigned short* Ks1 = Kp + r1 * 64 + sc1 * 8;
    const unsigned short* Ks2 = Kp + r2 * 64 + sc2 * 8;
    const unsigned short* Vs1 = Vp + r1 * 1024 + sc1 * 8;
    const unsigned short* Vs2 = Vp + r2 * 1024 + sc2 * 8;

    auto STAGE_K = [&](int buf, int kt) {
        __builtin_amdgcn_global_load_lds(GP(Ks1 + kt * 64), LP(&Kbuf[buf][0] + s1 * 8), 16, 0, 0);
        __builtin_amdgcn_global_load_lds(GP(Ks2 + kt * 64), LP(&Kbuf[buf][0] + s2 * 8), 16, 0, 0);
    };
    auto STAGE_V = [&](int buf, int kt) {
        __builtin_amdgcn_global_load_lds(GP(Vs1 + kt), LP(&Vbuf[buf][0] + s1 * 8), 16, 0, 0);
        __builtin_amdgcn_global_load_lds(GP(Vs2 + kt), LP(&Vbuf[buf][0] + s2 * 8), 16, 0, 0);
    };

    bf16x8 qfr[2];
#pragma unroll
    for (int kc = 0; kc < 2; kc++)
        qfr[kc] = *reinterpret_cast<const bf16x8*>(Qp + (qbase + lr) * 64 + kc * 32 + lg * 8);

    bf16x8 onesf;
#pragma unroll
    for (int j = 0; j < 8; j++) onesf[j] = (short)0x3F80;   // bf16 1.0 x8

    f32x4 o[4], l5;
#pragma unroll
    for (int df = 0; df < 4; df++)
#pragma unroll
        for (int r = 0; r < 4; r++) o[df][r] = 0.f;
#pragma unroll
    for (int r = 0; r < 4; r++) l5[r] = 0.f;

    auto QK = [&](f32x4 (&s)[4], const unsigned short* Kl) {
#pragma unroll
        for (int kf = 0; kf < 4; kf++)
#pragma unroll
            for (int r = 0; r < 4; r++) s[kf][r] = 0.f;
        __builtin_amdgcn_s_setprio(1);
#pragma unroll
        for (int kc = 0; kc < 2; kc++) {
#pragma unroll
            for (int kf = 0; kf < 4; kf++) {
                const int row = ((kf >> 1) << 5) + ((kf & 1) << 2) + koff;
                const int col = (kc * 4 + lg) ^ ((row & 3) | ((row >> 1) & 4));
                const bf16x8 kfr = *reinterpret_cast<const bf16x8*>(Kl + row * 64 + col * 8);
                s[kf] = __builtin_amdgcn_mfma_f32_16x16x32_bf16(kfr, qfr[kc], s[kf], 0, 0, 0);
            }
        }
        __builtin_amdgcn_s_setprio(0);
    };

    auto EXPpack = [&](f32x4 (&s)[4], bf16x8 (&pfr)[2]) {
#pragma unroll
        for (int kf = 0; kf < 4; kf++)
#pragma unroll
            for (int r = 0; r < 4; r++) s[kf][r] = exp2f(s[kf][r]);
#pragma unroll
        for (int kc = 0; kc < 2; kc++) {
            union { bf16x8 v; unsigned u[4]; } pk;
            pk.u[0] = cvt_pk_bf16(s[2 * kc][0], s[2 * kc][1]);
            pk.u[1] = cvt_pk_bf16(s[2 * kc][2], s[2 * kc][3]);
            pk.u[2] = cvt_pk_bf16(s[2 * kc + 1][0], s[2 * kc + 1][1]);
            pk.u[3] = cvt_pk_bf16(s[2 * kc + 1][2], s[2 * kc + 1][3]);
            pfr[kc] = pk.v;
        }
    };

    auto PV = [&](const unsigned short* Vl, bf16x8 (&pfr)[2]) {
        __builtin_amdgcn_s_setprio(1);
#pragma unroll
        for (int kc = 0; kc < 2; kc++) {
            l5 = __builtin_amdgcn_mfma_f32_16x16x32_bf16(onesf, pfr[kc], l5, 0, 0, 0);
#pragma unroll
            for (int df = 0; df < 4; df++) {
                const int vrow = df * 16 + lr;
                const int vcol = (kc * 4 + lg) ^ ((vrow & 3) | ((vrow >> 1) & 4));
                const bf16x8 vfr = *reinterpret_cast<const bf16x8*>(Vl + vrow * 64 + vcol * 8);
                o[df] = __builtin_amdgcn_mfma_f32_16x16x32_bf16(vfr, pfr[kc], o[df], 0, 0, 0);
            }
        }
        __builtin_amdgcn_s_setprio(0);
    };

    STAGE_K(0, 0);
    STAGE_K(1, 64);
    STAGE_V(0, 0);
    asm volatile("s_waitcnt vmcnt(0)" ::: "memory");
    __builtin_amdgcn_s_barrier();
    __builtin_amdgcn_sched_barrier(0);
    f32x4 sE[4], sO[4];
    QK(sE, &Kbuf[0][0]);

    bf16x8 pfr[2];
#pragma unroll 1
    for (int tt = 0; tt < 8; tt++) {
        const int t0 = 2 * tt, t1 = 2 * tt + 1;
        STAGE_K(0, (t0 + 2 < 16 ? t0 + 2 : 15) * 64);
        STAGE_V(1, t1 * 64);
        EXPpack(sE, pfr);
        asm volatile("s_waitcnt vmcnt(4)" ::: "memory");
        __builtin_amdgcn_s_barrier();
        __builtin_amdgcn_sched_barrier(0);
        QK(sO, &Kbuf[1][0]);
        PV(&Vbuf[0][0], pfr);
        __builtin_amdgcn_s_barrier();
        __builtin_amdgcn_sched_barrier(0);
        STAGE_K(1, (t1 + 2 < 16 ? t1 + 2 : 15) * 64);
        STAGE_V(0, (t1 + 1 < 16 ? t1 + 1 : 15) * 64);
        EXPpack(sO, pfr);
        asm volatile("s_waitcnt vmcnt(4)" ::: "memory");
        __builtin_amdgcn_s_barrier();
        __builtin_amdgcn_sched_barrier(0);
        if (tt < 7) QK(sE, &Kbuf[0][0]);
        PV(&Vbuf[1][0], pfr);
        __builtin_amdgcn_s_barrier();
        __builtin_amdgcn_sched_barrier(0);
    }

    const int b = bh >> 4, h = bh & 15;
    const float rinv = 1.f / l5[0];
    const int q = qbase + lr;
#pragma unroll
    for (int df = 0; df < 4; df++) {
        us4 pk;
        pk.x = f2bf(o[df][0] * rinv); pk.y = f2bf(o[df][1] * rinv);
        pk.z = f2bf(o[df][2] * rinv); pk.w = f2bf(o[df][3] * rinv);
        *reinterpret_cast<us4*>(AO + (size_t)(b * 1024 + q) * 1024 + h * 64 + df * 16 + lg * 4) = pk;
    }
}

// ---------------- GEMM2: out = AO @ proj_w^T + proj_b (fp32), tile 128x64, BK=64 ----
__global__ __launch_bounds__(256, 3) void gemm_proj_kernel(
        const unsigned short* __restrict__ A, const unsigned short* __restrict__ Bw,
        const float* __restrict__ bias, float* __restrict__ out) {
    __shared__ __align__(16) unsigned short As[2 * 8192];
    __shared__ __align__(16) unsigned short Bs[2 * 4096];
    const int tid = threadIdx.x;
    const int lane = tid & 63;
    const int wv = tid >> 6;
    const int wr = wv >> 1, wc = wv & 1;
    const int tm = blockIdx.y, tn = blockIdx.x;
    const int lr = lane & 15, lg = lane >> 4;

    const unsigned short* Ag[4];
    const unsigned short* Bg[2];
    int doffA[4], doffB[2];
#pragma unroll
    for (int j = 0; j < 4; j++) {
        const int c = tid + j * 256;
        const int row = c >> 3, sl = c & 7;
        const int gs = (sl ^ ((row & 3) | ((row >> 1) & 4))) * 8;
        Ag[j] = A + (size_t)(tm * 128 + row) * 1024 + gs;
        doffA[j] = c * 8;
    }
#pragma unroll
    for (int j = 0; j < 2; j++) {
        const int c = tid + j * 256;
        const int row = c >> 3, sl = c & 7;
        const int gs = (sl ^ ((row & 3) | ((row >> 1) & 4))) * 8;
        Bg[j] = Bw + (size_t)(tn * 64 + row) * 1024 + gs;
        doffB[j] = c * 8;
    }

    f32x4 acc[4][2];
#pragma unroll
    for (int i = 0; i < 4; i++)
#pragma unroll
        for (int j = 0; j < 2; j++)
#pragma unroll
            for (int q = 0; q < 4; q++) acc[i][j][q] = 0.f;

    auto STAGE = [&](int buf, int k0) {
#pragma unroll
        for (int j = 0; j < 4; j++)
            __builtin_amdgcn_global_load_lds(GP(Ag[j] + k0), LP(As + buf * 8192 + doffA[j]), 16, 0, 0);
#pragma unroll
        for (int j = 0; j < 2; j++)
            __builtin_amdgcn_global_load_lds(GP(Bg[j] + k0), LP(Bs + buf * 4096 + doffB[j]), 16, 0, 0);
    };

    STAGE(0, 0);
    for (int t = 0; t < 16; t++) {
        const int buf = t & 1;
        if (t < 15) {
            STAGE(buf ^ 1, (t + 1) * 64);
            asm volatile("s_waitcnt vmcnt(6)" ::: "memory");
        } else {
            asm volatile("s_waitcnt vmcnt(0)" ::: "memory");
        }
        __builtin_amdgcn_s_barrier();
        __builtin_amdgcn_sched_barrier(0);

        bf16x8 af[4][2], bfv[2][2];
#pragma unroll
        for (int i = 0; i < 4; i++)
#pragma unroll
            for (int kk = 0; kk < 2; kk++) {
                const int ra = wr * 64 + i * 16 + lr;
                af[i][kk] = *reinterpret_cast<const bf16x8*>(
                    As + buf * 8192 + ra * 64 + ((kk * 4 + lg) ^ ((ra & 3) | ((ra >> 1) & 4))) * 8);
            }
#pragma unroll
        for (int j = 0; j < 2; j++)
#pragma unroll
            for (int kk = 0; kk < 2; kk++) {
                const int rb = wc * 32 + j * 16 + lr;
                bfv[j][kk] = *reinterpret_cast<const bf16x8*>(
                    Bs + buf * 4096 + rb * 64 + ((kk * 4 + lg) ^ ((rb & 3) | ((rb >> 1) & 4))) * 8);
            }
        __builtin_amdgcn_s_setprio(1);
#pragma unroll
        for (int i = 0; i < 4; i++)
#pragma unroll
            for (int j = 0; j < 2; j++)
#pragma unroll
                for (int kk = 0; kk < 2; kk++)
                    acc[i][j] = __builtin_amdgcn_mfma_f32_16x16x32_bf16(af[i][kk], bfv[j][kk], acc[i][j], 0, 0, 0);
        __builtin_amdgcn_s_setprio(0);
        __builtin_amdgcn_s_barrier();
        __builtin_amdgcn_sched_barrier(0);
    }

#pragma unroll
    for (int i = 0; i < 4; i++)
#pragma unroll
        for (int j = 0; j < 2; j++)
#pragma unroll
            for (int r = 0; r < 4; r++) {
                const int row = tm * 128 + wr * 64 + i * 16 + lg * 4 + r;
                const int col = tn * 64 + wc * 32 + j * 16 + lr;
                out[(size_t)row * 1024 + col] = acc[i][j][r] + bias[col];
            }
}

extern "C" void kernel_launch(void* const* d_in, const int* in_sizes, int n_in,
                              void* d_out, int out_size, void* d_ws, size_t ws_size,
                              hipStream_t stream) {
    const float* x      = (const float*)d_in[0];
    const float* cosT   = (const float*)d_in[1];
    const float* sinT   = (const float*)d_in[2];
    const float* qkv_w  = (const float*)d_in[3];
    const float* qkv_b  = (const float*)d_in[4];
    const float* proj_w = (const float*)d_in[5];
    const float* proj_b = (const float*)d_in[6];
    float* out = (float*)d_out;

    char* ws = (char*)d_ws;
    unsigned short* xb    = (unsigned short*)(ws);                 // 8 MB  [4096][1024]
    unsigned short* wqkv  = (unsigned short*)(ws + (8u << 20));    // 6 MB  [3072][1024]
    unsigned short* wproj = (unsigned short*)(ws + (14u << 20));   // 2 MB  [1024][1024]
    unsigned short* Qb    = (unsigned short*)(ws + (16u << 20));   // 8 MB  [64][1024][64]
    unsigned short* Kb    = (unsigned short*)(ws + (24u << 20));   // 8 MB  [64][1024][64]
    unsigned short* Vt    = (unsigned short*)(ws + (32u << 20));   // 8 MB  [64][64][1024]
    unsigned short* AO    = (unsigned short*)(ws + (40u << 20));   // 8 MB  [4096][1024]

    cvt3_kernel<<<2048, 256, 0, stream>>>(x, qkv_w, proj_w, xb, wqkv, wproj);
    gemm_qkv_kernel<<<dim3(12, 16), 512, 0, stream>>>(xb, wqkv, qkv_b, cosT, sinT, Qb, Kb, Vt);
    attn_kernel<<<dim3(64, 16), 256, 0, stream>>>(Qb, Kb, Vt, AO);
    gemm_proj_kernel<<<dim3(16, 32), 256, 0, stream>>>(AO, wproj, proj_b, out);
}

// Round 12
// 93.044 us; speedup vs baseline: 1.1048x; 1.1048x over previous
//
#include <hip/hip_runtime.h>

typedef __attribute__((ext_vector_type(8))) short bf16x8;
typedef __attribute__((ext_vector_type(4))) float f32x4;
typedef __attribute__((ext_vector_type(4))) unsigned short us4;

#define LOG2E 1.44269504088896f
#define GP(p) (const __attribute__((address_space(1))) void*)(p)
#define LP(p) (__attribute__((address_space(3))) void*)(p)

__device__ inline unsigned short f2bf(float f) {
    unsigned u = __float_as_uint(f);
    u += 0x7fffu + ((u >> 16) & 1u);
    return (unsigned short)(u >> 16);
}

__device__ inline unsigned cvt_pk_bf16(float lo, float hi) {
    unsigned r;
    asm("v_cvt_pk_bf16_f32 %0, %1, %2" : "=v"(r) : "v"(lo), "v"(hi));
    return r;
}

// ---------------- fused fp32 -> bf16 convert of x, qkv_w, proj_w ----------------
__global__ void cvt3_kernel(const float* __restrict__ x, const float* __restrict__ qw,
                            const float* __restrict__ pw,
                            unsigned short* __restrict__ xb, unsigned short* __restrict__ wqkv,
                            unsigned short* __restrict__ wproj) {
    const int nthreads = gridDim.x * blockDim.x;
    for (int i = blockIdx.x * blockDim.x + threadIdx.x; i < 2097152; i += nthreads) {
        const float* src; unsigned short* dst; int off;
        if (i < 1048576)      { src = x;  dst = xb;    off = i; }
        else if (i < 1835008) { src = qw; dst = wqkv;  off = i - 1048576; }
        else                  { src = pw; dst = wproj; off = i - 1835008; }
        const float4 v = *reinterpret_cast<const float4*>(src + off * 4);
        us4 o;
        o.x = f2bf(v.x); o.y = f2bf(v.y); o.z = f2bf(v.z); o.w = f2bf(v.w);
        *reinterpret_cast<us4*>(dst + off * 4) = o;
    }
}

// ---------------- 128^2 GEMM mainloop: double-buffered, counted vmcnt, swizzled ------
__device__ inline void gemm_mainloop_db(const unsigned short* __restrict__ A,
                                        const unsigned short* __restrict__ Bw,
                                        unsigned short* As, unsigned short* Bs,  // [2*4096] each
                                        int tm, int tn, f32x4 (&acc)[4][4]) {
    const int K = 1024;
    const int tid = threadIdx.x;
    const int lane = tid & 63;
    const int wv = tid >> 6;
    const int wr = wv >> 1, wc = wv & 1;
    const int lr = lane & 15, lg = lane >> 4;

    const int c1 = tid, c2 = tid + 256;
    const int r1 = c1 >> 2, r2 = c2 >> 2;
    const int g1 = ((c1 & 3) ^ ((r1 >> 1) & 3)) * 8;
    const int g2 = ((c2 & 3) ^ ((r2 >> 1) & 3)) * 8;
    const unsigned short* Ag1 = A + (size_t)(tm * 128 + r1) * K + g1;
    const unsigned short* Ag2 = A + (size_t)(tm * 128 + r2) * K + g2;
    const unsigned short* Bg1 = Bw + (size_t)(tn * 128 + r1) * K + g1;
    const unsigned short* Bg2 = Bw + (size_t)(tn * 128 + r2) * K + g2;

    const int rs = (lr >> 1) & 3;

    auto STAGE = [&](int buf, int k0) {
        __builtin_amdgcn_global_load_lds(GP(Ag1 + k0), LP(As + buf * 4096 + c1 * 8), 16, 0, 0);
        __builtin_amdgcn_global_load_lds(GP(Ag2 + k0), LP(As + buf * 4096 + c2 * 8), 16, 0, 0);
        __builtin_amdgcn_global_load_lds(GP(Bg1 + k0), LP(Bs + buf * 4096 + c1 * 8), 16, 0, 0);
        __builtin_amdgcn_global_load_lds(GP(Bg2 + k0), LP(Bs + buf * 4096 + c2 * 8), 16, 0, 0);
    };

    STAGE(0, 0);
    for (int t = 0; t < 32; t++) {
        const int buf = t & 1;
        if (t < 31) {
            STAGE(buf ^ 1, (t + 1) * 32);
            asm volatile("s_waitcnt vmcnt(4)" ::: "memory");
        } else {
            asm volatile("s_waitcnt vmcnt(0)" ::: "memory");
        }
        __builtin_amdgcn_s_barrier();
        __builtin_amdgcn_sched_barrier(0);

        bf16x8 af[4], bfv[4];
#pragma unroll
        for (int i = 0; i < 4; i++) {
            const int sl = (lg ^ rs) * 8;
            af[i]  = *reinterpret_cast<const bf16x8*>(As + buf * 4096 + (wr * 64 + i * 16 + lr) * 32 + sl);
            bfv[i] = *reinterpret_cast<const bf16x8*>(Bs + buf * 4096 + (wc * 64 + i * 16 + lr) * 32 + sl);
        }
        __builtin_amdgcn_s_setprio(1);
#pragma unroll
        for (int i = 0; i < 4; i++)
#pragma unroll
            for (int j = 0; j < 4; j++)
                acc[i][j] = __builtin_amdgcn_mfma_f32_16x16x32_bf16(af[i], bfv[j], acc[i][j], 0, 0, 0);
        __builtin_amdgcn_s_setprio(0);
        __builtin_amdgcn_s_barrier();
        __builtin_amdgcn_sched_barrier(0);
    }
}

// ---------------- GEMM1: qkv = x @ qkv_w^T + b, RoPE on q,k, scatter ----------------
__global__ __launch_bounds__(256, 4) void gemm_qkv_kernel(
        const unsigned short* __restrict__ A, const unsigned short* __restrict__ Bw,
        const float* __restrict__ bias, const float* __restrict__ cosT, const float* __restrict__ sinT,
        unsigned short* __restrict__ Qb, unsigned short* __restrict__ Kb, unsigned short* __restrict__ Vt) {
    __shared__ __align__(16) unsigned short As[2 * 4096];
    __shared__ __align__(16) unsigned short Bs[2 * 4096];
    const int tid = threadIdx.x;
    const int lane = tid & 63;
    const int wv = tid >> 6;
    const int wr = wv >> 1, wc = wv & 1;
    const int tm = blockIdx.y, tn = blockIdx.x;
    const int lr = lane & 15, lg = lane >> 4;

    f32x4 acc[4][4];
#pragma unroll
    for (int i = 0; i < 4; i++)
#pragma unroll
        for (int j = 0; j < 4; j++)
#pragma unroll
            for (int q = 0; q < 4; q++) acc[i][j][q] = 0.f;

    gemm_mainloop_db(A, Bw, As, Bs, tm, tn, acc);

    const int cbase = tn * 128 + wc * 64;
    const int sec = cbase >> 10;                   // 0=q 1=k 2=v
    const int h = (cbase & 1023) >> 6;
    float bias_c[4];
#pragma unroll
    for (int j = 0; j < 4; j++) bias_c[j] = bias[cbase + j * 16 + lr];

    if (sec == 2) {
#pragma unroll
        for (int i = 0; i < 4; i++) {
            const int m0 = tm * 128 + wr * 64 + i * 16 + lg * 4;
            const int b = m0 >> 10, n0 = m0 & 1023;
#pragma unroll
            for (int j = 0; j < 4; j++) {
                const int d = j * 16 + lr;
                us4 pk;
                pk.x = f2bf(acc[i][j][0] + bias_c[j]); pk.y = f2bf(acc[i][j][1] + bias_c[j]);
                pk.z = f2bf(acc[i][j][2] + bias_c[j]); pk.w = f2bf(acc[i][j][3] + bias_c[j]);
                *reinterpret_cast<us4*>(Vt + ((size_t)((b * 16 + h) * 64 + d)) * 1024 + n0) = pk;
            }
        }
    } else {
#pragma unroll
        for (int i = 0; i < 4; i++) {
#pragma unroll
            for (int r = 0; r < 4; r++) {
                const int m = tm * 128 + wr * 64 + i * 16 + lg * 4 + r;
                const int b = m >> 10, n = m & 1023;
                float vals[4];
#pragma unroll
                for (int j = 0; j < 4; j++) vals[j] = acc[i][j][r] + bias_c[j];
#pragma unroll
                for (int j = 0; j < 4; j++) {
                    const int d = j * 16 + lr;
                    const float c = cosT[n * 64 + d];
                    const float s = sinT[n * 64 + d];
                    const float pr = vals[j ^ 2];          // paired element d ^ 32
                    float outv = vals[j] * c + (d < 32 ? -pr : pr) * s;
                    if (sec == 0) outv *= 0.125f * LOG2E;  // fold scale + log2(e) into Q
                    unsigned short* dst = (sec == 0) ? Qb : Kb;
                    dst[((size_t)((b * 16 + h) * 1024 + n)) * 64 + d] = f2bf(outv);
                }
            }
        }
    }
}

// ---------------- flash attention: 32 q-rows/wave, NO-MAX softmax, ones-MFMA l ------
// grid (64 bh, 8 qt); 4 waves x 32 q-rows (2 q-frags) -> 512 blocks = 2/CU.
// Each kfr/vfr LDS read now feeds TWO MFMAs (per-MFMA LDS traffic halves vs QBLK=16);
// K/V staging L2 traffic halves (512 blocks stage vs 1024).
// Pipeline (per phase, staggered K/V, counted vmcnt, never 0 in loop):
//   STAGE_K(t+2) STAGE_V(t+1); EXPpack(t); vmcnt(4); bar; QK(t+1) || PV(t); bar.
__global__ __launch_bounds__(256, 2) void attn_kernel(
        const unsigned short* __restrict__ Qb, const unsigned short* __restrict__ Kb,
        const unsigned short* __restrict__ Vt, unsigned short* __restrict__ AO) {
    __shared__ __align__(16) unsigned short Kbuf[2][4096];
    __shared__ __align__(16) unsigned short Vbuf[2][4096];
    const int tid = threadIdx.x, lane = tid & 63, wv = tid >> 6;
    const int bh = blockIdx.x, qt = blockIdx.y;
    const int qbase = qt * 128 + wv * 32;
    const unsigned short* Qp = Qb + (size_t)bh * 65536;
    const unsigned short* Kp = Kb + (size_t)bh * 65536;
    const unsigned short* Vp = Vt + (size_t)bh * 65536;
    const int lr = lane & 15, lg = lane >> 4;
    const int koff = (lr >> 2) * 8 + (lr & 3);     // lane part of pi

    const int s1 = tid, s2 = tid + 256;
    const int r1 = s1 >> 3, r2 = s2 >> 3;
    const int sc1 = (s1 & 7) ^ ((r1 & 3) | ((r1 >> 1) & 4));
    const int sc2 = (s2 & 7) ^ ((r2 & 3) | ((r2 >> 1) & 4));
    const unsigned short* Ks1 = Kp + r1 * 64 + sc1 * 8;
    const unsigned short* Ks2 = Kp + r2 * 64 + sc2 * 8;
    const unsigned short* Vs1 = Vp + r1 * 1024 + sc1 * 8;
    const unsigned short* Vs2 = Vp + r2 * 1024 + sc2 * 8;

    auto STAGE_K = [&](int buf, int kt) {
        __builtin_amdgcn_global_load_lds(GP(Ks1 + kt * 64), LP(&Kbuf[buf][0] + s1 * 8), 16, 0, 0);
        __builtin_amdgcn_global_load_lds(GP(Ks2 + kt * 64), LP(&Kbuf[buf][0] + s2 * 8), 16, 0, 0);
    };
    auto STAGE_V = [&](int buf, int kt) {
        __builtin_amdgcn_global_load_lds(GP(Vs1 + kt), LP(&Vbuf[buf][0] + s1 * 8), 16, 0, 0);
        __builtin_amdgcn_global_load_lds(GP(Vs2 + kt), LP(&Vbuf[buf][0] + s2 * 8), 16, 0, 0);
    };

    bf16x8 qfr[2][2];                  // [qf][kc]
#pragma unroll
    for (int qf = 0; qf < 2; qf++)
#pragma unroll
        for (int kc = 0; kc < 2; kc++)
            qfr[qf][kc] = *reinterpret_cast<const bf16x8*>(Qp + (qbase + qf * 16 + lr) * 64 + kc * 32 + lg * 8);

    bf16x8 onesf;
#pragma unroll
    for (int j = 0; j < 8; j++) onesf[j] = (short)0x3F80;   // bf16 1.0 x8

    f32x4 o[4][2], l5[2];
#pragma unroll
    for (int df = 0; df < 4; df++)
#pragma unroll
        for (int qf = 0; qf < 2; qf++)
#pragma unroll
            for (int r = 0; r < 4; r++) o[df][qf][r] = 0.f;
#pragma unroll
    for (int qf = 0; qf < 2; qf++)
#pragma unroll
        for (int r = 0; r < 4; r++) l5[qf][r] = 0.f;

    // QK^T: s[kf][qf]; kfr read once, feeds both q-frags
    auto QK = [&](f32x4 (&s)[4][2], const unsigned short* Kl) {
#pragma unroll
        for (int kf = 0; kf < 4; kf++)
#pragma unroll
            for (int qf = 0; qf < 2; qf++)
#pragma unroll
                for (int r = 0; r < 4; r++) s[kf][qf][r] = 0.f;
        __builtin_amdgcn_s_setprio(1);
#pragma unroll
        for (int kc = 0; kc < 2; kc++) {
#pragma unroll
            for (int kf = 0; kf < 4; kf++) {
                const int row = ((kf >> 1) << 5) + ((kf & 1) << 2) + koff;
                const int col = (kc * 4 + lg) ^ ((row & 3) | ((row >> 1) & 4));
                const bf16x8 kfr = *reinterpret_cast<const bf16x8*>(Kl + row * 64 + col * 8);
                s[kf][0] = __builtin_amdgcn_mfma_f32_16x16x32_bf16(kfr, qfr[0][kc], s[kf][0], 0, 0, 0);
                s[kf][1] = __builtin_amdgcn_mfma_f32_16x16x32_bf16(kfr, qfr[1][kc], s[kf][1], 0, 0, 0);
            }
        }
        __builtin_amdgcn_s_setprio(0);
    };

    // exp2 + pack (no max tracking); pfr[kc][qf]
    auto EXPpack = [&](f32x4 (&s)[4][2], bf16x8 (&pfr)[2][2]) {
#pragma unroll
        for (int kf = 0; kf < 4; kf++)
#pragma unroll
            for (int qf = 0; qf < 2; qf++)
#pragma unroll
                for (int r = 0; r < 4; r++) s[kf][qf][r] = exp2f(s[kf][qf][r]);
#pragma unroll
        for (int kc = 0; kc < 2; kc++)
#pragma unroll
            for (int qf = 0; qf < 2; qf++) {
                union { bf16x8 v; unsigned u[4]; } pk;
                pk.u[0] = cvt_pk_bf16(s[2 * kc][qf][0], s[2 * kc][qf][1]);
                pk.u[1] = cvt_pk_bf16(s[2 * kc][qf][2], s[2 * kc][qf][3]);
                pk.u[2] = cvt_pk_bf16(s[2 * kc + 1][qf][0], s[2 * kc + 1][qf][1]);
                pk.u[3] = cvt_pk_bf16(s[2 * kc + 1][qf][2], s[2 * kc + 1][qf][3]);
                pfr[kc][qf] = pk.v;
            }
    };

    // PV: vfr read once, feeds both q-frags; ones-MFMA accumulates l per q-frag
    auto PV = [&](const unsigned short* Vl, bf16x8 (&pfr)[2][2]) {
        __builtin_amdgcn_s_setprio(1);
#pragma unroll
        for (int kc = 0; kc < 2; kc++) {
            l5[0] = __builtin_amdgcn_mfma_f32_16x16x32_bf16(onesf, pfr[kc][0], l5[0], 0, 0, 0);
            l5[1] = __builtin_amdgcn_mfma_f32_16x16x32_bf16(onesf, pfr[kc][1], l5[1], 0, 0, 0);
#pragma unroll
            for (int df = 0; df < 4; df++) {
                const int vrow = df * 16 + lr;
                const int vcol = (kc * 4 + lg) ^ ((vrow & 3) | ((vrow >> 1) & 4));
                const bf16x8 vfr = *reinterpret_cast<const bf16x8*>(Vl + vrow * 64 + vcol * 8);
                o[df][0] = __builtin_amdgcn_mfma_f32_16x16x32_bf16(vfr, pfr[kc][0], o[df][0], 0, 0, 0);
                o[df][1] = __builtin_amdgcn_mfma_f32_16x16x32_bf16(vfr, pfr[kc][1], o[df][1], 0, 0, 0);
            }
        }
        __builtin_amdgcn_s_setprio(0);
    };

    // prologue: K(0), K(1), V(0); drain; QK(0)
    STAGE_K(0, 0);
    STAGE_K(1, 64);
    STAGE_V(0, 0);
    asm volatile("s_waitcnt vmcnt(0)" ::: "memory");
    __builtin_amdgcn_s_barrier();
    __builtin_amdgcn_sched_barrier(0);
    f32x4 sE[4][2], sO[4][2];
    QK(sE, &Kbuf[0][0]);

    bf16x8 pfr[2][2];
#pragma unroll 1
    for (int tt = 0; tt < 8; tt++) {
        const int t0 = 2 * tt, t1 = 2 * tt + 1;
        // ---- even phase t0: scores sE, K from Kbuf[0], V from Vbuf[0] ----
        STAGE_K(0, (t0 + 2 < 16 ? t0 + 2 : 15) * 64);
        STAGE_V(1, t1 * 64);
        EXPpack(sE, pfr);
        asm volatile("s_waitcnt vmcnt(4)" ::: "memory");
        __builtin_amdgcn_s_barrier();
        __builtin_amdgcn_sched_barrier(0);
        QK(sO, &Kbuf[1][0]);          // QK(t0+1)
        PV(&Vbuf[0][0], pfr);         // PV(t0)
        __builtin_amdgcn_s_barrier();
        __builtin_amdgcn_sched_barrier(0);
        // ---- odd phase t1: scores sO, K from Kbuf[1], V from Vbuf[1] ----
        STAGE_K(1, (t1 + 2 < 16 ? t1 + 2 : 15) * 64);
        STAGE_V(0, (t1 + 1 < 16 ? t1 + 1 : 15) * 64);
        EXPpack(sO, pfr);
        asm volatile("s_waitcnt vmcnt(4)" ::: "memory");
        __builtin_amdgcn_s_barrier();
        __builtin_amdgcn_sched_barrier(0);
        if (tt < 7) QK(sE, &Kbuf[0][0]);   // QK(t1+1)
        PV(&Vbuf[1][0], pfr);              // PV(t1)
        __builtin_amdgcn_s_barrier();
        __builtin_amdgcn_sched_barrier(0);
    }

    // epilogue: l5[qf] components all equal row-sum for col q; no shuffles needed
    const int b = bh >> 4, h = bh & 15;
#pragma unroll
    for (int qf = 0; qf < 2; qf++) {
        const float rinv = 1.f / l5[qf][0];
        const int q = qbase + qf * 16 + lr;
#pragma unroll
        for (int df = 0; df < 4; df++) {
            us4 pk;
            pk.x = f2bf(o[df][qf][0] * rinv); pk.y = f2bf(o[df][qf][1] * rinv);
            pk.z = f2bf(o[df][qf][2] * rinv); pk.w = f2bf(o[df][qf][3] * rinv);
            *reinterpret_cast<us4*>(AO + (size_t)(b * 1024 + q) * 1024 + h * 64 + df * 16 + lg * 4) = pk;
        }
    }
}

// ---------------- GEMM2: out = AO @ proj_w^T + proj_b (fp32), tile 128x64, BK=64 ----
__global__ __launch_bounds__(256, 3) void gemm_proj_kernel(
        const unsigned short* __restrict__ A, const unsigned short* __restrict__ Bw,
        const float* __restrict__ bias, float* __restrict__ out) {
    __shared__ __align__(16) unsigned short As[2 * 8192];
    __shared__ __align__(16) unsigned short Bs[2 * 4096];
    const int tid = threadIdx.x;
    const int lane = tid & 63;
    const int wv = tid >> 6;
    const int wr = wv >> 1, wc = wv & 1;
    const int tm = blockIdx.y, tn = blockIdx.x;
    const int lr = lane & 15, lg = lane >> 4;

    const unsigned short* Ag[4];
    const unsigned short* Bg[2];
    int doffA[4], doffB[2];
#pragma unroll
    for (int j = 0; j < 4; j++) {
        const int c = tid + j * 256;
        const int row = c >> 3, sl = c & 7;
        const int gs = (sl ^ ((row & 3) | ((row >> 1) & 4))) * 8;
        Ag[j] = A + (size_t)(tm * 128 + row) * 1024 + gs;
        doffA[j] = c * 8;
    }
#pragma unroll
    for (int j = 0; j < 2; j++) {
        const int c = tid + j * 256;
        const int row = c >> 3, sl = c & 7;
        const int gs = (sl ^ ((row & 3) | ((row >> 1) & 4))) * 8;
        Bg[j] = Bw + (size_t)(tn * 64 + row) * 1024 + gs;
        doffB[j] = c * 8;
    }

    f32x4 acc[4][2];
#pragma unroll
    for (int i = 0; i < 4; i++)
#pragma unroll
        for (int j = 0; j < 2; j++)
#pragma unroll
            for (int q = 0; q < 4; q++) acc[i][j][q] = 0.f;

    auto STAGE = [&](int buf, int k0) {
#pragma unroll
        for (int j = 0; j < 4; j++)
            __builtin_amdgcn_global_load_lds(GP(Ag[j] + k0), LP(As + buf * 8192 + doffA[j]), 16, 0, 0);
#pragma unroll
        for (int j = 0; j < 2; j++)
            __builtin_amdgcn_global_load_lds(GP(Bg[j] + k0), LP(Bs + buf * 4096 + doffB[j]), 16, 0, 0);
    };

    STAGE(0, 0);
    for (int t = 0; t < 16; t++) {
        const int buf = t & 1;
        if (t < 15) {
            STAGE(buf ^ 1, (t + 1) * 64);
            asm volatile("s_waitcnt vmcnt(6)" ::: "memory");
        } else {
            asm volatile("s_waitcnt vmcnt(0)" ::: "memory");
        }
        __builtin_amdgcn_s_barrier();
        __builtin_amdgcn_sched_barrier(0);

        bf16x8 af[4][2], bfv[2][2];
#pragma unroll
        for (int i = 0; i < 4; i++)
#pragma unroll
            for (int kk = 0; kk < 2; kk++) {
                const int ra = wr * 64 + i * 16 + lr;
                af[i][kk] = *reinterpret_cast<const bf16x8*>(
                    As + buf * 8192 + ra * 64 + ((kk * 4 + lg) ^ ((ra & 3) | ((ra >> 1) & 4))) * 8);
            }
#pragma unroll
        for (int j = 0; j < 2; j++)
#pragma unroll
            for (int kk = 0; kk < 2; kk++) {
                const int rb = wc * 32 + j * 16 + lr;
                bfv[j][kk] = *reinterpret_cast<const bf16x8*>(
                    Bs + buf * 4096 + rb * 64 + ((kk * 4 + lg) ^ ((rb & 3) | ((rb >> 1) & 4))) * 8);
            }
        __builtin_amdgcn_s_setprio(1);
#pragma unroll
        for (int i = 0; i < 4; i++)
#pragma unroll
            for (int j = 0; j < 2; j++)
#pragma unroll
                for (int kk = 0; kk < 2; kk++)
                    acc[i][j] = __builtin_amdgcn_mfma_f32_16x16x32_bf16(af[i][kk], bfv[j][kk], acc[i][j], 0, 0, 0);
        __builtin_amdgcn_s_setprio(0);
        __builtin_amdgcn_s_barrier();
        __builtin_amdgcn_sched_barrier(0);
    }

#pragma unroll
    for (int i = 0; i < 4; i++)
#pragma unroll
        for (int j = 0; j < 2; j++)
#pragma unroll
            for (int r = 0; r < 4; r++) {
                const int row = tm * 128 + wr * 64 + i * 16 + lg * 4 + r;
                const int col = tn * 64 + wc * 32 + j * 16 + lr;
                out[(size_t)row * 1024 + col] = acc[i][j][r] + bias[col];
            }
}

extern "C" void kernel_launch(void* const* d_in, const int* in_sizes, int n_in,
                              void* d_out, int out_size, void* d_ws, size_t ws_size,
                              hipStream_t stream) {
    const float* x      = (const float*)d_in[0];
    const float* cosT   = (const float*)d_in[1];
    const float* sinT   = (const float*)d_in[2];
    const float* qkv_w  = (const float*)d_in[3];
    const float* qkv_b  = (const float*)d_in[4];
    const float* proj_w = (const float*)d_in[5];
    const float* proj_b = (const float*)d_in[6];
    float* out = (float*)d_out;

    char* ws = (char*)d_ws;
    unsigned short* xb    = (unsigned short*)(ws);                 // 8 MB  [4096][1024]
    unsigned short* wqkv  = (unsigned short*)(ws + (8u << 20));    // 6 MB  [3072][1024]
    unsigned short* wproj = (unsigned short*)(ws + (14u << 20));   // 2 MB  [1024][1024]
    unsigned short* Qb    = (unsigned short*)(ws + (16u << 20));   // 8 MB  [64][1024][64]
    unsigned short* Kb    = (unsigned short*)(ws + (24u << 20));   // 8 MB  [64][1024][64]
    unsigned short* Vt    = (unsigned short*)(ws + (32u << 20));   // 8 MB  [64][64][1024]
    unsigned short* AO    = (unsigned short*)(ws + (40u << 20));   // 8 MB  [4096][1024]

    cvt3_kernel<<<2048, 256, 0, stream>>>(x, qkv_w, proj_w, xb, wqkv, wproj);
    gemm_qkv_kernel<<<dim3(24, 32), 256, 0, stream>>>(xb, wqkv, qkv_b, cosT, sinT, Qb, Kb, Vt);
    attn_kernel<<<dim3(64, 8), 256, 0, stream>>>(Qb, Kb, Vt, AO);
    gemm_proj_kernel<<<dim3(16, 32), 256, 0, stream>>>(AO, wproj, proj_b, out);
}